// Round 12
// baseline (100.598 us; speedup 1.0000x reference)
//
#include <hip/hip_runtime.h>
#include <stdint.h>

#define BATCH    8
#define NITEMS   1000000
#define NTHR     125000        // NITEMS/8 threads, 8 items each
#define NBLKS    489           // ceil(NTHR/256)
#define BUFCAP   128           // per-block candidate segment (mean 64, +8 sigma)
#define NC       64
#define NF       4096
#define NF8      8192          // unified fine space over top-2 coarse bins
#define SBASE    62
#define THRESH   0.96875f      // 62/64, exact in fp32
#define MID63    0.984375f     // 63/64, exact in fp32
#define CAPC     32768         // cand capacity per batch
#define CANDCAP2 262144        // fallback boundary-bin list capacity
#define IMG_W    768.0f
#define IMG_H    432.0f

typedef unsigned long long ull;

static __device__ __forceinline__ float clip0(float v, float hi) {
    return fminf(fmaxf(v, 0.0f), hi);
}
static __device__ __forceinline__ int cbin(float s) {
    int g = (int)(s * (float)NC);                   // pow-2 mul: exact, monotone
    return g > NC - 1 ? NC - 1 : (g < 0 ? 0 : g);
}
static __device__ __forceinline__ int fbin(float s, int g) {
    int f = (int)(s * (float)(NC * NF)) - g * NF;   // pow-2 mul: exact, monotone
    return f > NF - 1 ? NF - 1 : (f < 0 ? 0 : f);
}
static __device__ __forceinline__ unsigned mkbits(float4 box, float s) {
    float x1 = clip0(box.x - box.z * 0.5f, IMG_W);
    float x2 = clip0(box.x + box.z * 0.5f, IMG_W);
    float y1 = clip0(box.y - box.w * 0.5f, IMG_H);
    float y2 = clip0(box.y + box.w * 0.5f, IMG_H);
    bool m = ((x2 - x1) > 16.0f) && ((y2 - y1) > 16.0f);
    return __float_as_uint(m ? s : 0.0f);
}
static __device__ __forceinline__ int g8of(float s) {
    int cb = (s >= MID63) ? 63 : 62;
    return (cb - SBASE) * NF + fbin(s, cb);
}

// ---- K1: scores stream -> per-block candidate segments (no global atomics) ----
__global__ __launch_bounds__(256)
void k_scores(const float* __restrict__ scores,
              const float4* __restrict__ rps,
              ull* __restrict__ clist,
              unsigned* __restrict__ blkCnt) {
    __shared__ ull buf[BUFCAP];
    __shared__ unsigned cnt;
    const int b = blockIdx.y, blk = blockIdx.x, tid = threadIdx.x;
    const int lane = tid & 63;
    if (tid == 0) cnt = 0u;
    __syncthreads();
    const float4* sp4 = (const float4*)(scores + (size_t)b * NITEMS);
    const int t = blk * 256 + tid;
    float4 a0 = make_float4(0, 0, 0, 0), a1 = make_float4(0, 0, 0, 0);
    const bool act = (t < NTHR);
    if (act) { a0 = sp4[2 * t]; a1 = sp4[2 * t + 1]; }
    float sv[8] = {a0.x, a0.y, a0.z, a0.w, a1.x, a1.y, a1.z, a1.w};
    const int i0 = t * 8;
    #pragma unroll
    for (int j = 0; j < 8; ++j) {
        bool q = act && (sv[j] >= THRESH);
        ull m = __ballot(q);
        if (m) {
            unsigned pre = (unsigned)__popcll(m & ((1ULL << lane) - 1ULL));
            int leader = __ffsll((long long)m) - 1;
            unsigned bse = 0;
            if (lane == leader) bse = atomicAdd(&cnt, (unsigned)__popcll(m));
            bse = (unsigned)__shfl((int)bse, leader);
            if (q) {
                unsigned s2 = bse + pre;
                if (s2 < BUFCAP)
                    buf[s2] = ((ull)__float_as_uint(sv[j]) << 32) |
                              (unsigned)(~(unsigned)(i0 + j));
            }
        }
    }
    __syncthreads();
    unsigned n = cnt;
    if (tid == 0) blkCnt[b * NBLKS + blk] = n;   // raw count (>BUFCAP => ovf)
    if (n > BUFCAP) n = BUFCAP;
    const size_t base = ((size_t)b * NBLKS + blk) * BUFCAP;
    for (unsigned i = tid; i < n; i += 256) {
        ull key = buf[i];
        unsigned idx = ~((unsigned)key);
        float4 box = rps[(size_t)b * NITEMS + idx];
        float s = __uint_as_float((unsigned)(key >> 32));
        clist[base + i] = mkbits(box, s) ? key : 0ull;   // mask applied inline
    }
}

// ---- K2: per-batch mega-kernel: hist+scan+compact+rank+output (LDS-only meta) ----
__global__ __launch_bounds__(1024)
void k_mega(const float* __restrict__ scores,
            const float4* __restrict__ rps,
            const ull* __restrict__ clist,
            const unsigned* __restrict__ blkCnt,
            ull* __restrict__ cand,
            ull* __restrict__ clist2,
            float* __restrict__ out,
            int K) {
    const int b = blockIdx.x, tid = threadIdx.x;
    __shared__ unsigned hsuf[NF8];              // immutable suffix bases
    __shared__ unsigned hctr[NF8];              // hist -> slot counters
    __shared__ unsigned sc[1024];
    __shared__ unsigned bc[576];                // block counts / coarse bins
    __shared__ unsigned s_fb8, s_tot, s_ovf, s_cbb, s_nab, s_n2;

    for (int k = tid; k < NBLKS; k += 1024) bc[k] = blkCnt[b * NBLKS + k];
    for (int k = tid; k < NF8; k += 1024) hctr[k] = 0u;
    if (tid == 0) s_ovf = 0u;
    __syncthreads();
    unsigned myovf = 0u;
    for (int k = tid; k < NBLKS; k += 1024) if (bc[k] > BUFCAP) myovf = 1u;
    if (myovf) atomicOr(&s_ovf, 1u);
    // ---- build 8192-bin histogram from per-block segments ----
    const size_t c0 = (size_t)b * NBLKS * BUFCAP;
    for (unsigned u = tid; u < NBLKS * BUFCAP; u += 1024) {
        unsigned kb = u / BUFCAP, i = u - kb * BUFCAP;
        unsigned n = bc[kb]; if (n > BUFCAP) n = BUFCAP;
        if (i >= n) continue;
        ull key = clist[c0 + u];
        if (!key) continue;
        float s = __uint_as_float((unsigned)(key >> 32));
        atomicAdd(&hctr[g8of(s)], 1u);
    }
    __syncthreads();
    // ---- suffix scan (8 bins/thread, descending) ----
    unsigned cw[8], pin[8], run = 0;
    #pragma unroll
    for (int k = 0; k < 8; ++k) {
        cw[k] = hctr[NF8 - 1 - (tid * 8 + k)];
        run += cw[k]; pin[k] = run;
    }
    sc[tid] = run; __syncthreads();
    unsigned x = run;
    for (int off = 1; off < 1024; off <<= 1) {
        unsigned tv = (tid >= off) ? sc[tid - off] : 0u;
        __syncthreads();
        x += tv; sc[tid] = x;
        __syncthreads();
    }
    const unsigned exclBase = x - run;
    const unsigned alive = sc[1023];
    if (tid == 0) { s_fb8 = 0u; s_tot = alive; }
    __syncthreads();
    #pragma unroll
    for (int k = 0; k < 8; ++k) {
        int g = NF8 - 1 - (tid * 8 + k);
        unsigned excl = exclBase + pin[k] - cw[k];
        hsuf[g] = excl;
        hctr[g] = excl;                         // slot counter base
        if (excl < (unsigned)K && excl + cw[k] >= (unsigned)K) {
            s_fb8 = (unsigned)g; s_tot = excl + cw[k];
        }
    }
    __syncthreads();
    const bool fast = (alive >= (unsigned)K) && (s_ovf == 0u) &&
                      (s_tot <= (unsigned)CAPC);
    if (fast) {
        // ---- compact ----
        const unsigned fb8v = s_fb8;
        for (unsigned u = tid; u < NBLKS * BUFCAP; u += 1024) {
            unsigned kb = u / BUFCAP, i = u - kb * BUFCAP;
            unsigned n = bc[kb]; if (n > BUFCAP) n = BUFCAP;
            if (i >= n) continue;
            ull key = clist[c0 + u];
            if (!key) continue;
            float s = __uint_as_float((unsigned)(key >> 32));
            int g8 = g8of(s);
            if ((unsigned)g8 < fb8v) continue;
            unsigned slot = atomicAdd(&hctr[g8], 1u);
            if (slot < CAPC) cand[(size_t)b * CAPC + slot] = key;
        }
        __syncthreads();
        // ---- rank + gather + write ----
        unsigned total = s_tot;
        for (unsigned p = tid; p < total; p += 1024) {
            ull key = cand[(size_t)b * CAPC + p];
            float s = __uint_as_float((unsigned)(key >> 32));
            int g8 = g8of(s);
            unsigned sbase = hsuf[g8];
            unsigned send = hctr[g8];
            if (send > total) send = total;
            unsigned rank = sbase;
            for (unsigned j = sbase; j < send; ++j)
                rank += (cand[(size_t)b * CAPC + j] > key) ? 1u : 0u;
            if (rank < (unsigned)K) {
                unsigned idx = ~((unsigned)key);
                if (idx >= (unsigned)NITEMS) idx = 0;
                float4 box = rps[(size_t)b * NITEMS + idx];
                float x1 = clip0(box.x - box.z * 0.5f, IMG_W);
                float x2 = clip0(box.x + box.z * 0.5f, IMG_W);
                float y1 = clip0(box.y - box.w * 0.5f, IMG_H);
                float y2 = clip0(box.y + box.w * 0.5f, IMG_H);
                float nw = x2 - x1, nh = y2 - y1;
                ((float4*)out)[(size_t)b * K + rank] =
                    make_float4(x1 + nw * 0.5f, y1 + nh * 0.5f, nw, nh);
                out[(size_t)BATCH * K * 4 + (size_t)b * K + rank] = s;
            }
        }
        return;
    }
    // ======== generic fallback (block-local, correctness-only) ========
    if (tid < NC) bc[tid] = 0u;
    __syncthreads();
    const size_t base = (size_t)b * NITEMS;
    for (int i = tid; i < NITEMS; i += 1024) {
        unsigned bits = mkbits(rps[base + i], scores[base + i]);
        if (bits) atomicAdd(&bc[cbin(__uint_as_float(bits))], 1u);
    }
    __syncthreads();
    if (tid == 0) {
        unsigned runc = 0, cbbv = 0, nabv = 0; bool found = false;
        for (int g = NC - 1; g >= 0; --g) {
            unsigned c = bc[g];
            bc[64 + g] = runc;                  // coarse suffix / slot base
            if (!found && runc < (unsigned)K && runc + c >= (unsigned)K) {
                cbbv = (unsigned)g; nabv = runc; found = true;
            }
            runc += c;
        }
        s_cbb = cbbv; s_nab = nabv; s_n2 = 0u;
    }
    __syncthreads();
    const unsigned cbb = s_cbb, nab = s_nab;
    if (tid < NC) hsuf[NF + tid] = bc[64 + tid];   // immutable coarse bases
    for (int k = tid; k < NF; k += 1024) hctr[k] = 0u;
    __syncthreads();
    for (int i = tid; i < NITEMS; i += 1024) {
        unsigned bits = mkbits(rps[base + i], scores[base + i]);
        if (!bits) continue;
        float s = __uint_as_float(bits);
        int g = cbin(s);
        if ((unsigned)g < cbb) continue;
        ull key = ((ull)bits << 32) | (unsigned)(~(unsigned)i);
        if ((unsigned)g > cbb) {
            unsigned slot = atomicAdd(&bc[64 + g], 1u);
            if (slot < CAPC) cand[(size_t)b * CAPC + slot] = key;
        } else {
            unsigned s2 = atomicAdd(&s_n2, 1u);
            if (s2 < CANDCAP2) clist2[(size_t)b * CANDCAP2 + s2] = key;
            atomicAdd(&hctr[fbin(s, (int)cbb)], 1u);
        }
    }
    __syncthreads();
    unsigned n2 = s_n2 > CANDCAP2 ? CANDCAP2 : s_n2;
    unsigned fcw[4], fpin[4], frun = 0;
    #pragma unroll
    for (int k = 0; k < 4; ++k) {
        fcw[k] = hctr[NF - 1 - (tid * 4 + k)];
        frun += fcw[k]; fpin[k] = frun;
    }
    sc[tid] = frun; __syncthreads();
    unsigned fx = frun;
    for (int off = 1; off < 1024; off <<= 1) {
        unsigned tv = (tid >= off) ? sc[tid - off] : 0u;
        __syncthreads();
        fx += tv; sc[tid] = fx;
        __syncthreads();
    }
    const unsigned fexcl = fx - frun;
    const unsigned ftot = sc[1023];
    if (tid == 0) { s_fb8 = 0u; s_tot = nab + ftot; }
    __syncthreads();
    #pragma unroll
    for (int k = 0; k < 4; ++k) {
        int g = NF - 1 - (tid * 4 + k);
        unsigned excl = fexcl + fpin[k] - fcw[k];
        hsuf[g] = nab + excl;
        unsigned t0 = nab + excl;
        if (t0 < (unsigned)K && t0 + fcw[k] >= (unsigned)K) {
            s_fb8 = (unsigned)g; s_tot = t0 + fcw[k];
        }
    }
    __syncthreads();
    #pragma unroll
    for (int k = 0; k < 4; ++k) {               // fine slot counters
        int g = NF - 1 - (tid * 4 + k);
        hctr[g] = hsuf[g];
    }
    __syncthreads();
    const unsigned fbv = s_fb8;
    for (unsigned i = tid; i < n2; i += 1024) {
        ull key = clist2[(size_t)b * CANDCAP2 + i];
        float s = __uint_as_float((unsigned)(key >> 32));
        int f = fbin(s, (int)cbb);
        if ((unsigned)f < fbv) continue;
        unsigned slot = atomicAdd(&hctr[f], 1u);
        if (slot < CAPC) cand[(size_t)b * CAPC + slot] = key;
    }
    __syncthreads();
    unsigned total = s_tot > CAPC ? CAPC : s_tot;
    for (unsigned p = tid; p < total; p += 1024) {
        ull key = cand[(size_t)b * CAPC + p];
        float s = __uint_as_float((unsigned)(key >> 32));
        int g = cbin(s);
        unsigned sbase, send;
        if ((unsigned)g > cbb) { sbase = hsuf[NF + g]; send = bc[64 + g]; }
        else { int f = fbin(s, (int)g); sbase = hsuf[f]; send = hctr[f]; }
        if (send > total) send = total;
        unsigned rank = sbase;
        for (unsigned j = sbase; j < send; ++j)
            rank += (cand[(size_t)b * CAPC + j] > key) ? 1u : 0u;
        if (rank < (unsigned)K) {
            unsigned idx = ~((unsigned)key);
            if (idx >= (unsigned)NITEMS) idx = 0;
            float4 box = rps[(size_t)b * NITEMS + idx];
            float x1 = clip0(box.x - box.z * 0.5f, IMG_W);
            float x2 = clip0(box.x + box.z * 0.5f, IMG_W);
            float y1 = clip0(box.y - box.w * 0.5f, IMG_H);
            float y2 = clip0(box.y + box.w * 0.5f, IMG_H);
            float nw = x2 - x1, nh = y2 - y1;
            ((float4*)out)[(size_t)b * K + rank] =
                make_float4(x1 + nw * 0.5f, y1 + nh * 0.5f, nw, nh);
            out[(size_t)BATCH * K * 4 + (size_t)b * K + rank] = s;
        }
    }
}

extern "C" void kernel_launch(void* const* d_in, const int* in_sizes, int n_in,
                              void* d_out, int out_size, void* d_ws, size_t ws_size,
                              hipStream_t stream) {
    const float*  scores = (const float*)d_in[0];
    const float4* rps    = (const float4*)d_in[1];
    const int K = out_size / (BATCH * 5);               // 12000

    // ---- workspace layout (non-overlapping; sizes verified) ----
    uint8_t* w = (uint8_t*)d_ws;
    ull* clist       = (ull*)(w);                       //         0 + 4,005,888
    unsigned* blkCnt = (unsigned*)(w + 4100000);        // 4,100,000 + 15,648
    ull* cand        = (ull*)(w + 4200000);             // 4,200,000 + 2,097,152
    ull* clist2      = (ull*)(w + 6400000);             // 6,400,000 + 16,777,216

    k_scores<<<dim3(NBLKS, BATCH), dim3(256), 0, stream>>>(scores, rps, clist, blkCnt);
    k_mega<<<dim3(BATCH), dim3(1024), 0, stream>>>(scores, rps, clist, blkCnt,
                                                   cand, clist2, (float*)d_out, K);
}